// Round 1
// baseline (169823.767 us; speedup 1.0000x reference)
//
#include <hip/hip_runtime.h>

#define T_ 512
#define B_ 64
#define D_ 1024
#define A_ 128
#define AIN_ 2176   // A + 2D
#define G4A_ 512    // 4A
#define PSZ_ 14336  // 14D

__device__ __forceinline__ float sigf(float x){ return 1.0f/(1.0f + __expf(-x)); }
__device__ __forceinline__ float tanhf_(float x){ return 2.0f/(1.0f + __expf(-2.0f*x)) - 1.0f; }

__global__ __launch_bounds__(256) void k_init(float* __restrict__ p, int n){
  int i = blockIdx.x*256 + threadIdx.x;
  if (i < n) p[i] = 0.0f;
}

// K1: a-LSTM gates. gates_t[n*64+b] = bih[n]+bhh[n]
//   + sum_k ax[b][k]*wih[n][k]  (ax = [xc(D), fh_l(D), ah_prev(A)])
//   + sum_k ah_self[b][k]*whh[n][k]
// thread: b = tid&63 (lane), n = blk*4 + (tid>>6). grid = 128.
__global__ __launch_bounds__(256) void k_again(
    const float* __restrict__ x_bmaj,   // layer0: &x[t][0][0] (b-major), else null
    const float* __restrict__ xc_t,     // layer1: fh_t[0] (feat-major), else null
    const float* __restrict__ fh_l,     // fh_t[l] (feat-major)
    const float* __restrict__ ah_prev,  // ah_t[l==0 ? 1 : 0]
    const float* __restrict__ ah_self,  // ah_t[l]
    const float* __restrict__ wih, const float* __restrict__ whh,
    const float* __restrict__ bih, const float* __restrict__ bhh,
    float* __restrict__ gates_t)
{
  __shared__ float xs[64*65];
  const int tid = threadIdx.x;
  const int b = tid & 63;
  const int n = blockIdx.x*4 + (tid >> 6);
  const float* wr = wih + (size_t)n*AIN_;
  float a0=0.f, a1=0.f, a2=0.f, a3=0.f;
  if (x_bmaj){
    // stage x chunks (b-major -> LDS transposed) for coalescing
    for (int k0 = 0; k0 < D_; k0 += 64){
      #pragma unroll
      for (int i = 0; i < 16; ++i){
        int idx = tid + i*256;
        int kk = idx & 63, bb = idx >> 6;
        xs[kk*65 + bb] = x_bmaj[bb*D_ + k0 + kk];
      }
      __syncthreads();
      #pragma unroll 8
      for (int k = 0; k < 64; k += 4){
        float4 w4 = *(const float4*)(wr + k0 + k);
        a0 += xs[(k+0)*65 + b] * w4.x;
        a1 += xs[(k+1)*65 + b] * w4.y;
        a2 += xs[(k+2)*65 + b] * w4.z;
        a3 += xs[(k+3)*65 + b] * w4.w;
      }
      __syncthreads();
    }
  } else {
    for (int k = 0; k < D_; k += 4){
      float4 w4 = *(const float4*)(wr + k);
      a0 += xc_t[(k+0)*64 + b] * w4.x;
      a1 += xc_t[(k+1)*64 + b] * w4.y;
      a2 += xc_t[(k+2)*64 + b] * w4.z;
      a3 += xc_t[(k+3)*64 + b] * w4.w;
    }
  }
  {
    const float* w2 = wr + D_;
    for (int k = 0; k < D_; k += 4){
      float4 w4 = *(const float4*)(w2 + k);
      a0 += fh_l[(k+0)*64 + b] * w4.x;
      a1 += fh_l[(k+1)*64 + b] * w4.y;
      a2 += fh_l[(k+2)*64 + b] * w4.z;
      a3 += fh_l[(k+3)*64 + b] * w4.w;
    }
  }
  {
    const float* w3 = wr + 2*D_;
    #pragma unroll 8
    for (int k = 0; k < A_; k += 4){
      float4 w4 = *(const float4*)(w3 + k);
      a0 += ah_prev[(k+0)*64 + b] * w4.x;
      a1 += ah_prev[(k+1)*64 + b] * w4.y;
      a2 += ah_prev[(k+2)*64 + b] * w4.z;
      a3 += ah_prev[(k+3)*64 + b] * w4.w;
    }
  }
  {
    const float* wh = whh + (size_t)n*A_;
    #pragma unroll 8
    for (int k = 0; k < A_; k += 4){
      float4 w4 = *(const float4*)(wh + k);
      a0 += ah_self[(k+0)*64 + b] * w4.x;
      a1 += ah_self[(k+1)*64 + b] * w4.y;
      a2 += ah_self[(k+2)*64 + b] * w4.z;
      a3 += ah_self[(k+3)*64 + b] * w4.w;
    }
  }
  gates_t[n*64 + b] = (a0 + a1) + (a2 + a3) + bih[n] + bhh[n];
}

// K2: a-cell (redundant per WG -> LDS; WG0 publishes ah/ac) + pol GEMM slice.
// Each WG owns 32 pol columns; for c<D writes xp0=pol*xc, c<2D writes hp1=pol*fh, else polp.
// grid = PSZ/32 = 448.
__global__ __launch_bounds__(256) void k_cellpol(
    const float* __restrict__ gates_t,
    const float* __restrict__ ac_old, float* __restrict__ ac_new,
    float* __restrict__ ah_out,
    const float* __restrict__ pw, const float* __restrict__ pb,
    const float* __restrict__ x_bmaj,  // layer0 xc (b-major) else null
    const float* __restrict__ xc_t,    // layer1 xc = fh_t[0] else null
    const float* __restrict__ fh_l,
    float* __restrict__ polp, float* __restrict__ xp0, float* __restrict__ hp1)
{
  __shared__ float ah_s[A_*64];
  const int tid = threadIdx.x;
  const int b = tid & 63;
  const int q = tid >> 6;
  // phase A: recompute a-cell
  #pragma unroll
  for (int j = q; j < A_; j += 4){
    float gi = gates_t[(j        )*64 + b];
    float gf = gates_t[(j +   A_ )*64 + b];
    float gg = gates_t[(j + 2*A_ )*64 + b];
    float go = gates_t[(j + 3*A_ )*64 + b];
    float c  = ac_old[j*64 + b];
    float c2 = sigf(gf)*c + sigf(gi)*tanhf_(gg);
    float h2 = sigf(go)*tanhf_(c2);
    ah_s[j*64 + b] = h2;
    if (blockIdx.x == 0){ ah_out[j*64 + b] = h2; ac_new[j*64 + b] = c2; }
  }
  __syncthreads();
  // phase B: pol slice, 8 cols per thread (stride 4)
  const int c0 = blockIdx.x*32 + q;
  float acc[8];
  const float* wrow[8];
  #pragma unroll
  for (int ci = 0; ci < 8; ++ci){
    int c = c0 + ci*4;
    wrow[ci] = pw + (size_t)c*A_;
    acc[ci] = pb[c];
  }
  for (int k = 0; k < A_; ++k){
    float av = ah_s[k*64 + b];
    #pragma unroll
    for (int ci = 0; ci < 8; ++ci) acc[ci] += av * wrow[ci][k];
  }
  #pragma unroll
  for (int ci = 0; ci < 8; ++ci){
    int c = c0 + ci*4;
    float v = acc[ci];
    if (c < D_){
      float xv = x_bmaj ? x_bmaj[b*D_ + c] : xc_t[c*64 + b];
      xp0[c*64 + b] = v * xv;
    } else if (c < 2*D_){
      hp1[(c - D_)*64 + b] = v * fh_l[(c - D_)*64 + b];
    } else {
      polp[(size_t)c*64 + b] = v;
    }
  }
}

// K3: fast-LSTM gates (two GEMMs K=1024 via LDS-staged xp0/hp1) + fused cell.
// thread: b = tid&63, j = blk*4 + (tid>>6); computes all 4 gates for (b,j). grid = 256.
__global__ __launch_bounds__(256) void k_fast(
    const float* __restrict__ xp0, const float* __restrict__ hp1,
    const float* __restrict__ fwih, const float* __restrict__ fwhh,
    const float* __restrict__ fb, const float* __restrict__ polp,
    float* __restrict__ fh_l, float* __restrict__ fc_l,
    float* __restrict__ out)  // &d_out[t][0][0] (b-major) if layer1, else null
{
  __shared__ float xs[128*64];
  __shared__ float hs[128*64];
  const int tid = threadIdx.x;
  const int b = tid & 63;
  const int j = blockIdx.x*4 + (tid >> 6);
  float accI[4] = {0.f,0.f,0.f,0.f};
  float accH[4] = {0.f,0.f,0.f,0.f};
  const float* wi[4]; const float* wh[4];
  #pragma unroll
  for (int g4 = 0; g4 < 4; ++g4){
    wi[g4] = fwih + (size_t)(g4*D_ + j)*D_;
    wh[g4] = fwhh + (size_t)(g4*D_ + j)*D_;
  }
  for (int k0 = 0; k0 < D_; k0 += 128){
    #pragma unroll
    for (int i = 0; i < 32; ++i){
      int idx = tid + i*256;
      xs[idx] = xp0[k0*64 + idx];
      hs[idx] = hp1[k0*64 + idx];
    }
    __syncthreads();
    for (int k = 0; k < 128; k += 4){
      float wiv[4][4], whv[4][4];
      #pragma unroll
      for (int g4 = 0; g4 < 4; ++g4){
        float4 a4 = *(const float4*)(wi[g4] + k0 + k);
        float4 b4 = *(const float4*)(wh[g4] + k0 + k);
        wiv[g4][0]=a4.x; wiv[g4][1]=a4.y; wiv[g4][2]=a4.z; wiv[g4][3]=a4.w;
        whv[g4][0]=b4.x; whv[g4][1]=b4.y; whv[g4][2]=b4.z; whv[g4][3]=b4.w;
      }
      #pragma unroll
      for (int kk = 0; kk < 4; ++kk){
        float xv = xs[(k+kk)*64 + b];
        float hv = hs[(k+kk)*64 + b];
        #pragma unroll
        for (int g4 = 0; g4 < 4; ++g4){
          accI[g4] += xv * wiv[g4][kk];
          accH[g4] += hv * whv[g4][kk];
        }
      }
    }
    __syncthreads();
  }
  float g[4];
  #pragma unroll
  for (int g4 = 0; g4 < 4; ++g4){
    int n = g4*D_ + j;
    g[g4] = accI[g4]*polp[(size_t)(2*D_  + n)*64 + b]
          + fb[n]   *polp[(size_t)(10*D_ + n)*64 + b]
          + accH[g4]*polp[(size_t)(6*D_  + n)*64 + b];
  }
  float c2 = sigf(g[1])*fc_l[j*64 + b] + sigf(g[0])*tanhf_(g[2]);
  float h2 = sigf(g[3])*tanhf_(c2);
  fc_l[j*64 + b] = c2;
  fh_l[j*64 + b] = h2;
  if (out) out[(size_t)b*D_ + j] = h2;
}

extern "C" void kernel_launch(void* const* d_in, const int* in_sizes, int n_in,
                              void* d_out, int out_size, void* d_ws, size_t ws_size,
                              hipStream_t stream) {
  const float* x = (const float*)d_in[0];
  const float* a_wih[2] = {(const float*)d_in[1],  (const float*)d_in[10]};
  const float* a_whh[2] = {(const float*)d_in[2],  (const float*)d_in[11]};
  const float* a_bih[2] = {(const float*)d_in[3],  (const float*)d_in[12]};
  const float* a_bhh[2] = {(const float*)d_in[4],  (const float*)d_in[13]};
  const float* p_w[2]   = {(const float*)d_in[5],  (const float*)d_in[14]};
  const float* p_b[2]   = {(const float*)d_in[6],  (const float*)d_in[15]};
  const float* f_wih[2] = {(const float*)d_in[7],  (const float*)d_in[16]};
  const float* f_whh[2] = {(const float*)d_in[8],  (const float*)d_in[17]};
  const float* f_b[2]   = {(const float*)d_in[9],  (const float*)d_in[18]};

  float* ws = (float*)d_ws;
  // workspace layout (all feat-major [feat][64]); recurrent state first (zeroed):
  float* ah_t    = ws;                        // 2 * A*B          = 16384
  float* ac_t    = ah_t + 2*A_*B_;            // 2 layers * 2 parity * A*B = 32768
  float* fh_t    = ac_t + 4*A_*B_;            // 2 * D*B          = 131072
  float* fc_t    = fh_t + 2*D_*B_;            // 2 * D*B          = 131072
  float* gates_t = fc_t + 2*D_*B_;            // 4A*B             = 32768
  float* polp    = gates_t + (size_t)G4A_*B_; // PSZ*B            = 917504
  float* xp0     = polp + (size_t)PSZ_*B_;    // D*B              = 65536
  float* hp1     = xp0 + D_*B_;               // D*B              = 65536

  const int nz = 2*A_*B_ + 4*A_*B_ + 2*D_*B_ + 2*D_*B_; // 311296 state floats
  hipLaunchKernelGGL(k_init, dim3((nz + 255)/256), dim3(256), 0, stream, ws, nz);

  for (int t = 0; t < T_; ++t){
    for (int l = 0; l < 2; ++l){
      const float* xb  = (l == 0) ? x + (size_t)t*B_*D_ : nullptr;
      const float* xct = (l == 0) ? nullptr : fh_t;      // fh_t[0]
      float* fh_l    = fh_t + (size_t)l*D_*B_;
      float* fc_l    = fc_t + (size_t)l*D_*B_;
      float* ah_l    = ah_t + (size_t)l*A_*B_;
      const float* ah_prev = (l == 0) ? ah_t + (size_t)1*A_*B_  // python ah[-1] = ah[1] (prev step)
                                      : ah_t;                   // ah[0] (this step)
      float* ac_old = ac_t + (size_t)(l*2 + (t & 1))*A_*B_;
      float* ac_new = ac_t + (size_t)(l*2 + ((t + 1) & 1))*A_*B_;

      hipLaunchKernelGGL(k_again, dim3(G4A_/4), dim3(256), 0, stream,
                         xb, xct, fh_l, ah_prev, ah_l,
                         a_wih[l], a_whh[l], a_bih[l], a_bhh[l], gates_t);

      hipLaunchKernelGGL(k_cellpol, dim3(PSZ_/32), dim3(256), 0, stream,
                         gates_t, ac_old, ac_new, ah_l,
                         p_w[l], p_b[l], xb, xct, fh_l,
                         polp, xp0, hp1);

      hipLaunchKernelGGL(k_fast, dim3(D_/4), dim3(256), 0, stream,
                         xp0, hp1, f_wih[l], f_whh[l], f_b[l], polp,
                         fh_l, fc_l,
                         (l == 1) ? (float*)d_out + (size_t)t*B_*D_ : nullptr);
    }
  }
}

// Round 2
// 87394.220 us; speedup vs baseline: 1.9432x; 1.9432x over previous
//
#include <hip/hip_runtime.h>

#define T_ 512
#define B_ 64
#define D_ 1024
#define A_ 128
#define KCAT_ 2304   // 2176 (wih) + 128 (whh)
#define PSZ_ 14336

typedef __attribute__((ext_vector_type(8))) short short8;
typedef __attribute__((ext_vector_type(4))) short short4_t;
typedef __attribute__((ext_vector_type(4))) float float4_t;

__device__ __forceinline__ float sigf(float x){ return 1.0f/(1.0f + __expf(-x)); }
__device__ __forceinline__ float tanhf_(float x){ return 2.0f/(1.0f + __expf(-2.0f*x)) - 1.0f; }

__device__ __forceinline__ short f2bf(float f){
  unsigned u = __builtin_bit_cast(unsigned, f);
  u += 0x7fffu + ((u >> 16) & 1u);           // RNE
  return (short)(u >> 16);
}
__device__ __forceinline__ float bf2f(short s){
  unsigned u = ((unsigned)(unsigned short)s) << 16;
  return __builtin_bit_cast(float, u);
}

// ---------- prep kernels (once per launch) ----------
__global__ __launch_bounds__(256) void pk_cat(const float* __restrict__ wih,
                                              const float* __restrict__ whh,
                                              short* __restrict__ dst){
  int c = blockIdx.x*256 + threadIdx.x;     // 0..2303
  int n = blockIdx.y;                       // 0..511
  if (c >= KCAT_) return;
  float v = (c < 2176) ? wih[(size_t)n*2176 + c] : whh[n*A_ + (c - 2176)];
  dst[(size_t)n*KCAT_ + c] = f2bf(v);
}
__global__ __launch_bounds__(256) void pk_conv(const float* __restrict__ src,
                                               short* __restrict__ dst, int n){
  int i = blockIdx.x*256 + threadIdx.x;
  if (i < n) dst[i] = f2bf(src[i]);
}

// ---------- K1: a-gates GEMM  gates[512][64] ----------
// grid = 128 blocks x 64 threads: block = (mtile = blk>>2, ntile = blk&3)
__global__ __launch_bounds__(64) void k1_gates(
    const short* __restrict__ Wcat,   // [512][2304] bf16
    const float* __restrict__ xf,     // l==0: x_t fp32 [64][1024], else null
    const short* __restrict__ xbf,    // l==1: fh_bf[0] [64][1024], else unused
    const short* __restrict__ fhbf,   // fh_bf[l]
    const short* __restrict__ ahp,    // ah_prev bf16 [64][128]
    const short* __restrict__ ahs,    // ah_self bf16 [64][128]
    const float* __restrict__ bih, const float* __restrict__ bhh,
    float* __restrict__ gates)
{
  const int lane = threadIdx.x;
  const int mt = blockIdx.x >> 2, nt = blockIdx.x & 3;
  const int row = lane & 15, quad = lane >> 4;
  const int m0 = mt*16;
  const short* wrow = Wcat + (size_t)(m0 + row)*KCAT_ + quad*8;
  const int bq = nt*16 + row;
  float4_t acc = {0.f,0.f,0.f,0.f};

  if (xf){
    const float* xp = xf + (size_t)bq*D_ + quad*8;
    #pragma unroll 4
    for (int ks = 0; ks < 32; ++ks){
      short8 a = *(const short8*)(wrow + ks*32);
      float4_t x0 = *(const float4_t*)(xp + ks*32);
      float4_t x1 = *(const float4_t*)(xp + ks*32 + 4);
      short8 bfr;
      #pragma unroll
      for (int i = 0; i < 4; ++i){ bfr[i] = f2bf(x0[i]); bfr[4+i] = f2bf(x1[i]); }
      acc = __builtin_amdgcn_mfma_f32_16x16x32_bf16(a, bfr, acc, 0, 0, 0);
    }
  } else {
    const short* xp = xbf + (size_t)bq*D_ + quad*8;
    #pragma unroll 4
    for (int ks = 0; ks < 32; ++ks){
      short8 a = *(const short8*)(wrow + ks*32);
      short8 bfr = *(const short8*)(xp + ks*32);
      acc = __builtin_amdgcn_mfma_f32_16x16x32_bf16(a, bfr, acc, 0, 0, 0);
    }
  }
  {
    const short* hp = fhbf + (size_t)bq*D_ + quad*8;
    #pragma unroll 4
    for (int ks = 0; ks < 32; ++ks){
      short8 a = *(const short8*)(wrow + 1024 + ks*32);
      short8 bfr = *(const short8*)(hp + ks*32);
      acc = __builtin_amdgcn_mfma_f32_16x16x32_bf16(a, bfr, acc, 0, 0, 0);
    }
  }
  {
    const short* pp = ahp + bq*A_ + quad*8;
    #pragma unroll
    for (int ks = 0; ks < 4; ++ks){
      short8 a = *(const short8*)(wrow + 2048 + ks*32);
      short8 bfr = *(const short8*)(pp + ks*32);
      acc = __builtin_amdgcn_mfma_f32_16x16x32_bf16(a, bfr, acc, 0, 0, 0);
    }
  }
  {
    const short* sp = ahs + bq*A_ + quad*8;
    #pragma unroll
    for (int ks = 0; ks < 4; ++ks){
      short8 a = *(const short8*)(wrow + 2176 + ks*32);
      short8 bfr = *(const short8*)(sp + ks*32);
      acc = __builtin_amdgcn_mfma_f32_16x16x32_bf16(a, bfr, acc, 0, 0, 0);
    }
  }
  const int b = nt*16 + row;
  const int n0 = m0 + quad*4;
  #pragma unroll
  for (int r = 0; r < 4; ++r){
    int n = n0 + r;
    gates[n*B_ + b] = acc[r] + bih[n] + bhh[n];
  }
}

// ---------- K2: a-cell (redundant per block) + pol GEMM ----------
// grid = 224 blocks x 256 threads; wave q handles mtile m0=(blk*4+q)*16
__global__ __launch_bounds__(256) void k2_cellpol(
    const float* __restrict__ gates,
    const float* __restrict__ ac_old, float* __restrict__ ac_new,
    short* __restrict__ ah_out,       // ah_bf[l][cur] [64][128]
    const short* __restrict__ pwbf,   // [14336][128] bf16
    const float* __restrict__ pb,
    const float* __restrict__ xf,     // l==0: x_t fp32, else null
    const short* __restrict__ xbf,    // l==1: fh_bf[0]
    const short* __restrict__ fhbf,   // fh_bf[l]
    float* __restrict__ polp,         // [64][12288] fp32 (p2|p3|p4)
    short* __restrict__ xp0, short* __restrict__ hp1)  // bf16 [64][1024]
{
  __shared__ short ah_s[64*136];
  const int tid = threadIdx.x;
  const int b = tid & 63, q = tid >> 6;
  // phase A: cell
  for (int jj = 0; jj < 32; ++jj){
    int j = q*32 + jj;
    float gi = gates[(j      )*B_ + b];
    float gf = gates[(j + 128)*B_ + b];
    float gg = gates[(j + 256)*B_ + b];
    float go = gates[(j + 384)*B_ + b];
    float c  = ac_old[j*B_ + b];
    float c2 = sigf(gf)*c + sigf(gi)*tanhf_(gg);
    float h2 = sigf(go)*tanhf_(c2);
    ah_s[b*136 + j] = f2bf(h2);
    if (blockIdx.x == 0){
      ac_new[j*B_ + b] = c2;
      ah_out[b*A_ + j] = f2bf(h2);
    }
  }
  __syncthreads();
  // phase B: pol GEMM slice (M-tile of 16 per wave)
  const int lane = tid & 63;
  const int row = lane & 15, quad = lane >> 4;
  const int m0 = (blockIdx.x*4 + q)*16;
  const short* wrow = pwbf + (size_t)(m0 + row)*A_ + quad*8;
  float4_t acc[4] = {{0.f,0.f,0.f,0.f},{0.f,0.f,0.f,0.f},{0.f,0.f,0.f,0.f},{0.f,0.f,0.f,0.f}};
  #pragma unroll
  for (int ks = 0; ks < 4; ++ks){
    short8 a = *(const short8*)(wrow + ks*32);
    #pragma unroll
    for (int nt = 0; nt < 4; ++nt){
      short8 bf8 = *(const short8*)&ah_s[(nt*16 + row)*136 + ks*32 + quad*8];
      acc[nt] = __builtin_amdgcn_mfma_f32_16x16x32_bf16(a, bf8, acc[nt], 0, 0, 0);
    }
  }
  const int c0 = m0 + quad*4;
  float4_t pbv = *(const float4_t*)(pb + c0);
  if (m0 < 1024){
    #pragma unroll
    for (int nt = 0; nt < 4; ++nt){
      int b2 = nt*16 + row;
      float4_t xv;
      if (xf){ xv = *(const float4_t*)(xf + (size_t)b2*D_ + c0); }
      else {
        short4_t xb = *(const short4_t*)(xbf + (size_t)b2*D_ + c0);
        #pragma unroll
        for (int r = 0; r < 4; ++r) xv[r] = bf2f(xb[r]);
      }
      short4_t o;
      #pragma unroll
      for (int r = 0; r < 4; ++r) o[r] = f2bf((acc[nt][r] + pbv[r]) * xv[r]);
      *(short4_t*)(xp0 + (size_t)b2*D_ + c0) = o;
    }
  } else if (m0 < 2048){
    int cc = c0 - 1024;
    #pragma unroll
    for (int nt = 0; nt < 4; ++nt){
      int b2 = nt*16 + row;
      short4_t hb = *(const short4_t*)(fhbf + (size_t)b2*D_ + cc);
      short4_t o;
      #pragma unroll
      for (int r = 0; r < 4; ++r) o[r] = f2bf((acc[nt][r] + pbv[r]) * bf2f(hb[r]));
      *(short4_t*)(hp1 + (size_t)b2*D_ + cc) = o;
    }
  } else {
    int cc = c0 - 2048;
    #pragma unroll
    for (int nt = 0; nt < 4; ++nt){
      int b2 = nt*16 + row;
      float4_t vv;
      #pragma unroll
      for (int r = 0; r < 4; ++r) vv[r] = acc[nt][r] + pbv[r];
      *(float4_t*)(polp + (size_t)b2*12288 + cc) = vv;
    }
  }
}

// ---------- K3: f-gates (two bf16 GEMMs K=1024) + f-cell ----------
// grid = 64 blocks x 256 threads: block = jtile, wave q = ntile
__global__ __launch_bounds__(256) void k3_fast(
    const short* __restrict__ wI,     // fwih_bf [4096][1024]
    const short* __restrict__ wH,     // fwhh_bf
    const short* __restrict__ xp0, const short* __restrict__ hp1,  // bf16 [64][1024]
    const float* __restrict__ polp,   // [64][12288]
    const float* __restrict__ fb,
    float* __restrict__ fc,           // fp32 [64][1024]
    short* __restrict__ fhbf,         // bf16 [64][1024]
    float* __restrict__ outp)         // l==1: d_out + t*B*D else null
{
  const int tid = threadIdx.x;
  const int lane = tid & 63, nt = tid >> 6;
  const int row = lane & 15, quad = lane >> 4;
  const int j0 = blockIdx.x*16;
  const short* wIr[4]; const short* wHr[4];
  #pragma unroll
  for (int g = 0; g < 4; ++g){
    wIr[g] = wI + (size_t)(g*D_ + j0 + row)*D_ + quad*8;
    wHr[g] = wH + (size_t)(g*D_ + j0 + row)*D_ + quad*8;
  }
  const short* bx = xp0 + (size_t)(nt*16 + row)*D_ + quad*8;
  const short* bh = hp1 + (size_t)(nt*16 + row)*D_ + quad*8;
  float4_t aI[4] = {{0.f,0.f,0.f,0.f},{0.f,0.f,0.f,0.f},{0.f,0.f,0.f,0.f},{0.f,0.f,0.f,0.f}};
  float4_t aH[4] = {{0.f,0.f,0.f,0.f},{0.f,0.f,0.f,0.f},{0.f,0.f,0.f,0.f},{0.f,0.f,0.f,0.f}};
  #pragma unroll 2
  for (int ks = 0; ks < 32; ++ks){
    const int kg = ks*32;
    short8 bxf = *(const short8*)(bx + kg);
    short8 bhf = *(const short8*)(bh + kg);
    #pragma unroll
    for (int g = 0; g < 4; ++g){
      short8 ai = *(const short8*)(wIr[g] + kg);
      short8 ah = *(const short8*)(wHr[g] + kg);
      aI[g] = __builtin_amdgcn_mfma_f32_16x16x32_bf16(ai, bxf, aI[g], 0, 0, 0);
      aH[g] = __builtin_amdgcn_mfma_f32_16x16x32_bf16(ah, bhf, aH[g], 0, 0, 0);
    }
  }
  const int b = nt*16 + row;
  const int jr = j0 + quad*4;
  float4_t gl[4];
  #pragma unroll
  for (int g = 0; g < 4; ++g){
    const float* pbase = polp + (size_t)b*12288 + g*D_ + jr;
    float4_t p2 = *(const float4_t*)(pbase);
    float4_t p3 = *(const float4_t*)(pbase + 4096);
    float4_t p4 = *(const float4_t*)(pbase + 8192);
    float4_t fbv = *(const float4_t*)(fb + g*D_ + jr);
    #pragma unroll
    for (int r = 0; r < 4; ++r)
      gl[g][r] = aI[g][r]*p2[r] + fbv[r]*p4[r] + aH[g][r]*p3[r];
  }
  float4_t cold = *(const float4_t*)(fc + (size_t)b*D_ + jr);
  float4_t cnew, hnew;
  #pragma unroll
  for (int r = 0; r < 4; ++r){
    float c2 = sigf(gl[1][r])*cold[r] + sigf(gl[0][r])*tanhf_(gl[2][r]);
    float h2 = sigf(gl[3][r])*tanhf_(c2);
    cnew[r] = c2; hnew[r] = h2;
  }
  *(float4_t*)(fc + (size_t)b*D_ + jr) = cnew;
  short4_t hb;
  #pragma unroll
  for (int r = 0; r < 4; ++r) hb[r] = f2bf(hnew[r]);
  *(short4_t*)(fhbf + (size_t)b*D_ + jr) = hb;
  if (outp) *(float4_t*)(outp + (size_t)b*D_ + jr) = hnew;
}

extern "C" void kernel_launch(void* const* d_in, const int* in_sizes, int n_in,
                              void* d_out, int out_size, void* d_ws, size_t ws_size,
                              hipStream_t stream) {
  const float* x = (const float*)d_in[0];
  const float* a_wih[2] = {(const float*)d_in[1],  (const float*)d_in[10]};
  const float* a_whh[2] = {(const float*)d_in[2],  (const float*)d_in[11]};
  const float* a_bih[2] = {(const float*)d_in[3],  (const float*)d_in[12]};
  const float* a_bhh[2] = {(const float*)d_in[4],  (const float*)d_in[13]};
  const float* p_w[2]   = {(const float*)d_in[5],  (const float*)d_in[14]};
  const float* p_b[2]   = {(const float*)d_in[6],  (const float*)d_in[15]};
  const float* f_wih[2] = {(const float*)d_in[7],  (const float*)d_in[16]};
  const float* f_whh[2] = {(const float*)d_in[8],  (const float*)d_in[17]};
  const float* f_b[2]   = {(const float*)d_in[9],  (const float*)d_in[18]};

  char* w = (char*)d_ws;
  float* gates = (float*)(w + 0);          // 512*64*4        = 131072
  float* ac    = (float*)(w + 131072);     // [l][par][128*64]= 131072
  float* fc    = (float*)(w + 262144);     // [l][64*1024]    = 524288
  float* polp  = (float*)(w + 786432);     // 64*12288*4      = 3145728
  short* xp0   = (short*)(w + 3932160);    // 64*1024*2       = 131072
  short* hp1   = (short*)(w + 4063232);    // 131072
  short* fhbf  = (short*)(w + 4194304);    // [l][64*1024]    = 262144
  short* ahbf  = (short*)(w + 4456448);    // [l][par][64*128]= 65536
  short* Wcat  = (short*)(w + 4521984);    // [l][512*2304]   = 4718592
  short* pwbf  = (short*)(w + 9240576);    // [l][14336*128]  = 7340032
  short* fwihb = (short*)(w + 16580608);   // [l][4096*1024]  = 16777216
  short* fwhhb = (short*)(w + 33357824);   // 16777216 -> end 50135040

  // zero recurrent state: ac+fc, fh_bf+ah_bf
  hipMemsetAsync(w + 131072, 0, 655360, stream);
  hipMemsetAsync(w + 4194304, 0, 327680, stream);

  // weight conversion
  for (int l = 0; l < 2; ++l){
    pk_cat<<<dim3(9,512), 256, 0, stream>>>(a_wih[l], a_whh[l], Wcat + (size_t)l*512*KCAT_);
    pk_conv<<<(PSZ_*A_ + 255)/256, 256, 0, stream>>>(p_w[l], pwbf + (size_t)l*PSZ_*A_, PSZ_*A_);
    pk_conv<<<(4*D_*D_ + 255)/256, 256, 0, stream>>>(f_wih[l], fwihb + (size_t)l*4*D_*D_, 4*D_*D_);
    pk_conv<<<(4*D_*D_ + 255)/256, 256, 0, stream>>>(f_whh[l], fwhhb + (size_t)l*4*D_*D_, 4*D_*D_);
  }

  for (int t = 0; t < T_; ++t){
    const int par = t & 1, cur = par ^ 1;
    const float* xt = x + (size_t)t*B_*D_;
    for (int l = 0; l < 2; ++l){
      const float* xf  = (l == 0) ? xt : nullptr;
      const short* xbf = fhbf;                        // layer0 fh (used when l==1)
      const short* fh_l = fhbf + (size_t)l*B_*D_;
      const short* ahp = (l == 0) ? ahbf + (1*2 + par)*B_*A_   // ah[-1] = ah1 prev step
                                  : ahbf + (0*2 + cur)*B_*A_;  // ah[0] this step
      const short* ahs = ahbf + (l*2 + par)*B_*A_;
      short* ah_out    = ahbf + (l*2 + cur)*B_*A_;
      const float* ac_old = ac + (l*2 + par)*A_*B_;
      float* ac_new       = ac + (l*2 + cur)*A_*B_;

      k1_gates<<<128, 64, 0, stream>>>(
          Wcat + (size_t)l*512*KCAT_, xf, xbf, fh_l, ahp, ahs,
          a_bih[l], a_bhh[l], gates);

      k2_cellpol<<<224, 256, 0, stream>>>(
          gates, ac_old, ac_new, ah_out,
          pwbf + (size_t)l*PSZ_*A_, p_b[l], xf, xbf, fh_l,
          polp, xp0, hp1);

      k3_fast<<<64, 256, 0, stream>>>(
          fwihb + (size_t)l*4*D_*D_, fwhhb + (size_t)l*4*D_*D_,
          xp0, hp1, polp, f_b[l],
          fc + (size_t)l*B_*D_, (short*)fh_l,
          (l == 1) ? (float*)d_out + (size_t)t*B_*D_ : nullptr);
    }
  }
}